// Round 5
// baseline (231.014 us; speedup 1.0000x reference)
//
#include <hip/hip_runtime.h>
#include <hip/hip_bf16.h>

#define CCH 512
#define TTT 1024
#define BBB 8
#define NGRP 32
#define CPG 16
#define NHEAD 8
#define CHD 64
#define O_QKV 1536

typedef __attribute__((ext_vector_type(8))) short bf16x8;
typedef __attribute__((ext_vector_type(8))) unsigned short u16x8;
typedef __attribute__((ext_vector_type(4))) float f32x4;

__device__ __forceinline__ float us2f(unsigned short u) {
  union { unsigned int i; float f; } p; p.i = ((unsigned int)u) << 16; return p.f;
}
__device__ __forceinline__ unsigned short f2us(float f) {
  __hip_bfloat16 b = __float2bfloat16(f);
  return *reinterpret_cast<unsigned short*>(&b);
}

// ---------------- W f32 -> bf16 pre-convert ----------------
__global__ __launch_bounds__(256) void wcvt_kernel(
    const float* __restrict__ w, unsigned short* __restrict__ o, int n4)
{
  const int i = blockIdx.x * 256 + threadIdx.x;
  if (i < n4) {
    float4 v = reinterpret_cast<const float4*>(w)[i];
    ushort4 u;
    u.x = f2us(v.x); u.y = f2us(v.y); u.z = f2us(v.z); u.w = f2us(v.w);
    reinterpret_cast<ushort4*>(o)[i] = u;
  }
}

// ---------------- GroupNorm: f32 [b][c][t] -> bf16 hT [b][t][c] ----------------
__global__ __launch_bounds__(256) void gn_kernel(
    const float* __restrict__ x,
    const float* __restrict__ gw,
    const float* __restrict__ gb,
    unsigned short* __restrict__ hT)
{
  const int bg = blockIdx.x;
  const int bb = bg >> 5, g = bg & 31;
  const size_t base = ((size_t)bb * CCH + (size_t)g * CPG) * TTT;
  const float4* xv = reinterpret_cast<const float4*>(x + base);
  const int tid = threadIdx.x;

  float s = 0.f, q = 0.f;
  for (int i = tid; i < 4096; i += 256) {
    float4 u = xv[i];
    s += (u.x + u.y) + (u.z + u.w);
    q += u.x * u.x + u.y * u.y + u.z * u.z + u.w * u.w;
  }
  #pragma unroll
  for (int off = 32; off > 0; off >>= 1) {
    s += __shfl_down(s, off);
    q += __shfl_down(q, off);
  }
  __shared__ float red[10];
  const int wid = tid >> 6, lane = tid & 63;
  if (lane == 0) { red[wid] = s; red[4 + wid] = q; }
  __syncthreads();
  if (tid == 0) {
    float S = red[0] + red[1] + red[2] + red[3];
    float Q = red[4] + red[5] + red[6] + red[7];
    float mu = S * (1.f / 16384.f);
    float var = Q * (1.f / 16384.f) - mu * mu;
    red[8] = mu;
    red[9] = rsqrtf(var + 1e-5f);
  }
  __syncthreads();
  const float mu = red[8], rstd = red[9];
  float wsc[16], wbs[16];
  #pragma unroll
  for (int cc = 0; cc < 16; cc++) {
    wsc[cc] = gw[g * CPG + cc] * rstd;
    wbs[cc] = gb[g * CPG + cc] - mu * wsc[cc];
  }
  // transposed write: hT[b][t][512], our 16-channel slice at col g*16
  for (int tt = tid; tt < TTT; tt += 256) {
    u16x8 r0, r1;
    #pragma unroll
    for (int cc = 0; cc < 8; cc++)
      r0[cc] = f2us(fmaf(x[base + (size_t)cc * TTT + tt], wsc[cc], wbs[cc]));
    #pragma unroll
    for (int cc = 0; cc < 8; cc++)
      r1[cc] = f2us(fmaf(x[base + (size_t)(cc + 8) * TTT + tt], wsc[cc + 8], wbs[cc + 8]));
    u16x8* dst = reinterpret_cast<u16x8*>(&hT[((size_t)bb * TTT + tt) * CCH + g * CPG]);
    dst[0] = r0;
    dst[1] = r1;
  }
}

// ---------------- LDS-free MFMA GEMM ----------------
// out[b,o,t] = sum_c W[o,c] * Bm[b,t,c] + bias[o]  (Bm is [t][c] transposed)
// MODE 0: split bf16 outputs Q/K -> [bh][t][64] , V -> [bh][64][t]
// MODE 1: f32 out [b][o][t] + resid
template<int MODE>
__global__ __launch_bounds__(256) void gemm_g(
    const unsigned short* __restrict__ Wb,    // (O, 512) bf16
    const unsigned short* __restrict__ Bm,    // (B, 1024, 512) bf16
    const float* __restrict__ bias,           // (O)
    const float* __restrict__ resid,          // (B, O, 1024) f32 (MODE 1)
    unsigned short* __restrict__ oq,
    unsigned short* __restrict__ ok,
    unsigned short* __restrict__ ov,
    float* __restrict__ of,
    const int O)
{
  const int tid = threadIdx.x;
  const int bz = blockIdx.z;
  const int o0 = blockIdx.y * 128;
  const int t0 = blockIdx.x * 128;
  const int lane = tid & 63, w = tid >> 6;
  const int lg = lane >> 4, lr = lane & 15;
  const int wr = w >> 1, wc = w & 1;

  const unsigned short* Wrow = Wb + (size_t)(o0 + wr * 64) * CCH;
  const unsigned short* Brow = Bm + ((size_t)bz * TTT + t0 + wc * 64) * CCH;

  f32x4 acc[4][4];
  #pragma unroll
  for (int m = 0; m < 4; m++)
    #pragma unroll
    for (int n = 0; n < 4; n++) acc[m][n] = f32x4{0.f, 0.f, 0.f, 0.f};

  #pragma unroll 2
  for (int kt = 0; kt < CCH; kt += 64) {
    bf16x8 af[2][4], bf[2][4];
    #pragma unroll
    for (int k2 = 0; k2 < 2; k2++)
      #pragma unroll
      for (int m = 0; m < 4; m++)
        af[k2][m] = *reinterpret_cast<const bf16x8*>(
            &Wrow[(size_t)(m * 16 + lr) * CCH + kt + k2 * 32 + lg * 8]);
    #pragma unroll
    for (int k2 = 0; k2 < 2; k2++)
      #pragma unroll
      for (int n = 0; n < 4; n++)
        bf[k2][n] = *reinterpret_cast<const bf16x8*>(
            &Brow[(size_t)(n * 16 + lr) * CCH + kt + k2 * 32 + lg * 8]);
    #pragma unroll
    for (int k2 = 0; k2 < 2; k2++)
      #pragma unroll
      for (int n = 0; n < 4; n++)
        #pragma unroll
        for (int m = 0; m < 4; m++)
          acc[m][n] = __builtin_amdgcn_mfma_f32_16x16x32_bf16(af[k2][m], bf[k2][n], acc[m][n], 0, 0, 0);
  }

  if (MODE == 0) {
    const int a = (o0 >> 6) + wr;            // 64-channel block index, 0..23
    const int head = a / 3, part = a - head * 3;
    const size_t bhq = (size_t)bz * NHEAD + head;
    #pragma unroll
    for (int m = 0; m < 4; m++) {
      #pragma unroll
      for (int r = 0; r < 4; r++) {
        const int cl = m * 16 + lg * 4 + r;  // channel within 64-block
        const float bi = bias[a * 64 + cl];
        #pragma unroll
        for (int n = 0; n < 4; n++) {
          const int t = t0 + wc * 64 + n * 16 + lr;
          const float v = acc[m][n][r] + bi;
          if (part == 0)
            oq[(bhq * TTT + t) * CHD + cl] = f2us(v);
          else if (part == 1)
            ok[(bhq * TTT + t) * CHD + cl] = f2us(v);
          else
            ov[(bhq * CHD + cl) * TTT + t] = f2us(v);
        }
      }
    }
  } else {
    #pragma unroll
    for (int m = 0; m < 4; m++) {
      #pragma unroll
      for (int r = 0; r < 4; r++) {
        const int o = o0 + wr * 64 + m * 16 + lg * 4 + r;
        const float bi = bias[o];
        const size_t rowbase = ((size_t)bz * O + o) * TTT + t0 + wc * 64 + lr;
        #pragma unroll
        for (int n = 0; n < 4; n++) {
          const size_t idx = rowbase + n * 16;
          of[idx] = acc[m][n][r] + bi + resid[idx];
        }
      }
    }
  }
}

// ---------------- staging-free MFMA flash attention ----------------
// Q,K from [bh][t][64] global frags; V from [bh][64][t]; LDS only for P
// (wave-private slice -> NO barriers). Output avT [b][t][512].
__global__ __launch_bounds__(256) void attn_g(
    const unsigned short* __restrict__ qT,
    const unsigned short* __restrict__ kT,
    const unsigned short* __restrict__ vb,
    unsigned short* __restrict__ avT)
{
  const int bh = blockIdx.y;
  const int b = bh >> 3, hh = bh & 7;
  const int t0 = blockIdx.x * 64;
  const int tid = threadIdx.x;
  const int lane = tid & 63, w = tid >> 6;
  const int lg = lane >> 4, lr = lane & 15;

  __shared__ __align__(16) unsigned short pS[4][16][72];

  const unsigned short* qbase = qT + (size_t)bh * TTT * CHD;
  const unsigned short* kbase = kT + (size_t)bh * TTT * CHD;
  const unsigned short* vbase = vb + (size_t)bh * CHD * TTT;

  const bf16x8 aq0 = *reinterpret_cast<const bf16x8*>(&qbase[(size_t)(t0 + w * 16 + lr) * CHD + lg * 8]);
  const bf16x8 aq1 = *reinterpret_cast<const bf16x8*>(&qbase[(size_t)(t0 + w * 16 + lr) * CHD + lg * 8 + 32]);

  f32x4 opv[4];
  #pragma unroll
  for (int cn = 0; cn < 4; cn++) opv[cn] = f32x4{0.f, 0.f, 0.f, 0.f};
  float mrow[4] = {-1e30f, -1e30f, -1e30f, -1e30f};
  float lrow[4] = {0.f, 0.f, 0.f, 0.f};

  for (int sb = 0; sb < TTT; sb += 64) {
    // QK^T from global K frags
    f32x4 sc[4];
    #pragma unroll
    for (int sn = 0; sn < 4; sn++) {
      const unsigned short* kr = &kbase[(size_t)(sb + sn * 16 + lr) * CHD + lg * 8];
      const bf16x8 bk0 = *reinterpret_cast<const bf16x8*>(kr);
      const bf16x8 bk1 = *reinterpret_cast<const bf16x8*>(kr + 32);
      f32x4 t = __builtin_amdgcn_mfma_f32_16x16x32_bf16(aq0, bk0, f32x4{0.f, 0.f, 0.f, 0.f}, 0, 0, 0);
      sc[sn] = __builtin_amdgcn_mfma_f32_16x16x32_bf16(aq1, bk1, t, 0, 0, 0);
    }

    // prefetch V frags (latency hides under softmax)
    bf16x8 bv[4][2];
    #pragma unroll
    for (int cn = 0; cn < 4; cn++) {
      const unsigned short* vrow = &vbase[(size_t)(cn * 16 + lr) * TTT + sb + lg * 8];
      bv[cn][0] = *reinterpret_cast<const bf16x8*>(vrow);
      bv[cn][1] = *reinterpret_cast<const bf16x8*>(vrow + 32);
    }

    // online softmax
    float pv[4][4];
    #pragma unroll
    for (int sn = 0; sn < 4; sn++)
      #pragma unroll
      for (int r = 0; r < 4; r++) pv[sn][r] = sc[sn][r] * 0.125f;

    float rescale[4];
    #pragma unroll
    for (int r = 0; r < 4; r++) {
      float mx = fmaxf(fmaxf(pv[0][r], pv[1][r]), fmaxf(pv[2][r], pv[3][r]));
      mx = fmaxf(mx, __shfl_xor(mx, 1));
      mx = fmaxf(mx, __shfl_xor(mx, 2));
      mx = fmaxf(mx, __shfl_xor(mx, 4));
      mx = fmaxf(mx, __shfl_xor(mx, 8));
      const float mn = fmaxf(mrow[r], mx);
      rescale[r] = __expf(mrow[r] - mn);
      mrow[r] = mn;
      float rs = 0.f;
      #pragma unroll
      for (int sn = 0; sn < 4; sn++) {
        pv[sn][r] = __expf(pv[sn][r] - mn);
        rs += pv[sn][r];
      }
      lrow[r] = lrow[r] * rescale[r] + rs;
    }
    #pragma unroll
    for (int cn = 0; cn < 4; cn++)
      #pragma unroll
      for (int r = 0; r < 4; r++) opv[cn][r] *= rescale[r];

    // P -> wave-private LDS (no barrier: same-wave DS ordering)
    #pragma unroll
    for (int sn = 0; sn < 4; sn++)
      #pragma unroll
      for (int r = 0; r < 4; r++)
        pS[w][lg * 4 + r][sn * 16 + lr] = f2us(pv[sn][r]);

    const bf16x8 ap0 = *reinterpret_cast<const bf16x8*>(&pS[w][lr][lg * 8]);
    const bf16x8 ap1 = *reinterpret_cast<const bf16x8*>(&pS[w][lr][lg * 8 + 32]);
    #pragma unroll
    for (int cn = 0; cn < 4; cn++) {
      opv[cn] = __builtin_amdgcn_mfma_f32_16x16x32_bf16(ap0, bv[cn][0], opv[cn], 0, 0, 0);
      opv[cn] = __builtin_amdgcn_mfma_f32_16x16x32_bf16(ap1, bv[cn][1], opv[cn], 0, 0, 0);
    }
  }

  float inv[4];
  #pragma unroll
  for (int r = 0; r < 4; r++) {
    float v = lrow[r];
    v += __shfl_xor(v, 1);
    v += __shfl_xor(v, 2);
    v += __shfl_xor(v, 4);
    v += __shfl_xor(v, 8);
    inv[r] = 1.f / v;
  }
  // transposed output: avT[b][t][512], channel = hh*64 + cn*16 + lr
  #pragma unroll
  for (int cn = 0; cn < 4; cn++)
    #pragma unroll
    for (int r = 0; r < 4; r++)
      avT[((size_t)b * TTT + t0 + w * 16 + lg * 4 + r) * CCH + hh * CHD + cn * 16 + lr]
          = f2us(opv[cn][r] * inv[r]);
}

extern "C" void kernel_launch(void* const* d_in, const int* in_sizes, int n_in,
                              void* d_out, int out_size, void* d_ws, size_t ws_size,
                              hipStream_t stream) {
  const float* x      = (const float*)d_in[0];
  const float* gn_w   = (const float*)d_in[1];
  const float* gn_b   = (const float*)d_in[2];
  const float* qkv_w  = (const float*)d_in[3];
  const float* qkv_b  = (const float*)d_in[4];
  const float* proj_w = (const float*)d_in[5];
  const float* proj_b = (const float*)d_in[6];
  float* out = (float*)d_out;

  const size_t HT = (size_t)BBB * TTT * CCH;            // 4,194,304 elems
  const size_t QK = (size_t)BBB * NHEAD * TTT * CHD;    // 4,194,304 elems
  unsigned short* hT   = (unsigned short*)d_ws;         // [b][t][512]
  unsigned short* vbuf = hT + HT;                       // [bh][64][t]
  unsigned short* avT  = vbuf + QK;                     // [b][t][512]
  unsigned short* wq   = avT + HT;                      // (1536,512) bf16
  unsigned short* wp   = wq + (size_t)O_QKV * CCH;      // (512,512) bf16
  // Q^T/K^T live in d_out (16 MB f32): fully rewritten each launch,
  // consumed by attn before proj overwrites d_out (stream-ordered).
  unsigned short* qTd = (unsigned short*)d_out;         // [bh][t][64]
  unsigned short* kTd = qTd + QK;

  wcvt_kernel<<<dim3((O_QKV * CCH / 4 + 255) / 256), 256, 0, stream>>>(qkv_w, wq, O_QKV * CCH / 4);
  wcvt_kernel<<<dim3((CCH * CCH / 4 + 255) / 256), 256, 0, stream>>>(proj_w, wp, CCH * CCH / 4);
  gn_kernel<<<dim3(BBB * NGRP), 256, 0, stream>>>(x, gn_w, gn_b, hT);
  gemm_g<0><<<dim3(TTT / 128, O_QKV / 128, BBB), 256, 0, stream>>>(
      wq, hT, qkv_b, nullptr, qTd, kTd, vbuf, nullptr, O_QKV);
  attn_g<<<dim3(TTT / 64, BBB * NHEAD), 256, 0, stream>>>(qTd, kTd, vbuf, avT);
  gemm_g<1><<<dim3(TTT / 128, CCH / 128, BBB), 256, 0, stream>>>(
      wp, avT, proj_b, x, nullptr, nullptr, nullptr, out, CCH);
}

// Round 6
// 131.005 us; speedup vs baseline: 1.7634x; 1.7634x over previous
//
#include <hip/hip_runtime.h>
#include <hip/hip_bf16.h>

#define CCH 512
#define TTT 1024
#define BBB 8
#define NGRP 32
#define CPG 16
#define NHEAD 8
#define CHD 64
#define O_QKV 1536

typedef __attribute__((ext_vector_type(8))) short bf16x8;
typedef __attribute__((ext_vector_type(4))) short s16x4;
typedef __attribute__((ext_vector_type(4))) float f32x4;

__device__ __forceinline__ float us2f(unsigned short u) {
  union { unsigned int i; float f; } p; p.i = ((unsigned int)u) << 16; return p.f;
}
__device__ __forceinline__ unsigned short f2us(float f) {
  __hip_bfloat16 b = __float2bfloat16(f);
  return *reinterpret_cast<unsigned short*>(&b);
}
__device__ __forceinline__ bf16x8 cat8(s16x4 a, s16x4 b) {
  bf16x8 r;
  r[0] = a[0]; r[1] = a[1]; r[2] = a[2]; r[3] = a[3];
  r[4] = b[0]; r[5] = b[1]; r[6] = b[2]; r[7] = b[3];
  return r;
}

// Packed layout for a logical [R rows][K cols] bf16 matrix consumed as MFMA frags:
//   subtile (rt=row/16, kt=k/16) base = (rt*(K/16)+kt)*256
//   within: ((k%16)/4)*64 + (row%16)*4 + (k%4)
// Frag load (row, k0=half*32+lg*8, 8 elems): two b64 at
//   ((rt*(K/16) + k0/16 + lg/2)*256 + (lg&1)*128 + (row%16)*4) and +64.

// ---------------- W f32 -> packed bf16 ----------------
__global__ __launch_bounds__(256) void wpack_kernel(
    const float* __restrict__ wf, unsigned short* __restrict__ op, int nslot)
{
  const int s = blockIdx.x * 256 + threadIdx.x;   // one ushort4 slot
  if (s >= nslot) return;
  const int u = s & 63, sub = s >> 6;
  const int kt = sub & 31, rt = sub >> 5;         // K = 512 -> 32 kt
  const int lg = u >> 4, lr = u & 15;
  float4 v = *reinterpret_cast<const float4*>(&wf[(size_t)(rt * 16 + lr) * CCH + kt * 16 + lg * 4]);
  ushort4 r;
  r.x = f2us(v.x); r.y = f2us(v.y); r.z = f2us(v.z); r.w = f2us(v.w);
  reinterpret_cast<ushort4*>(op)[s] = r;
}

// ---------------- GroupNorm: f32 [b][c][t] -> packed H (row=t, k=c) ----------------
__global__ __launch_bounds__(256) void gn_kernel(
    const float* __restrict__ x,
    const float* __restrict__ gw,
    const float* __restrict__ gb,
    unsigned short* __restrict__ hP)
{
  const int bg = blockIdx.x;
  const int bb = bg >> 5, g = bg & 31;
  const size_t base = ((size_t)bb * CCH + (size_t)g * CPG) * TTT;
  const float4* xv = reinterpret_cast<const float4*>(x + base);
  const int tid = threadIdx.x;

  float s = 0.f, q = 0.f;
  for (int i = tid; i < 4096; i += 256) {
    float4 u = xv[i];
    s += (u.x + u.y) + (u.z + u.w);
    q += u.x * u.x + u.y * u.y + u.z * u.z + u.w * u.w;
  }
  #pragma unroll
  for (int off = 32; off > 0; off >>= 1) {
    s += __shfl_down(s, off);
    q += __shfl_down(q, off);
  }
  __shared__ float red[10];
  const int wid = tid >> 6, lane = tid & 63;
  if (lane == 0) { red[wid] = s; red[4 + wid] = q; }
  __syncthreads();
  if (tid == 0) {
    float S = red[0] + red[1] + red[2] + red[3];
    float Q = red[4] + red[5] + red[6] + red[7];
    float mu = S * (1.f / 16384.f);
    float var = Q * (1.f / 16384.f) - mu * mu;
    red[8] = mu;
    red[9] = rsqrtf(var + 1e-5f);
  }
  __syncthreads();
  const float mu = red[8], rstd = red[9];
  float wsc[16], wbs[16];
  #pragma unroll
  for (int cc = 0; cc < 16; cc++) {
    wsc[cc] = gw[g * CPG + cc] * rstd;
    wbs[cc] = gb[g * CPG + cc] - mu * wsc[cc];
  }
  for (int tt = tid; tt < TTT; tt += 256) {
    float v[16];
    #pragma unroll
    for (int cc = 0; cc < 16; cc++)
      v[cc] = fmaf(x[base + (size_t)cc * TTT + tt], wsc[cc], wbs[cc]);
    unsigned short* dst = &hP[(size_t)bb * 524288 + ((size_t)((tt >> 4) * 32 + g)) * 256 + (tt & 15) * 4];
    #pragma unroll
    for (int l2 = 0; l2 < 4; l2++) {
      ushort4 st;
      st.x = f2us(v[l2 * 4 + 0]);
      st.y = f2us(v[l2 * 4 + 1]);
      st.z = f2us(v[l2 * 4 + 2]);
      st.w = f2us(v[l2 * 4 + 3]);
      *reinterpret_cast<ushort4*>(&dst[l2 * 64]) = st;
    }
  }
}

// ---------------- LDS-free packed MFMA GEMM ----------------
// acc[b,o,t] = sum_c W[o,c] * H[b,t,c] + bias[o]
// MODE 0: Q/K -> packed(row=t,k=c within head-64), V -> packed(row=c,k=t)
// MODE 1: f32 natural out [b][o][t] + resid
template<int MODE>
__global__ __launch_bounds__(256) void gemm_p(
    const unsigned short* __restrict__ Ap,    // packed W
    const unsigned short* __restrict__ Bp,    // packed H/avT per b
    const float* __restrict__ bias,
    const float* __restrict__ resid,
    unsigned short* __restrict__ oq,
    unsigned short* __restrict__ ok,
    unsigned short* __restrict__ ov,
    float* __restrict__ of,
    const int O)
{
  const int tid = threadIdx.x;
  const int bz = blockIdx.z, o0 = blockIdx.y << 7, t0 = blockIdx.x << 7;
  const int lane = tid & 63, w = tid >> 6;
  const int lg = lane >> 4, lr = lane & 15;
  const int wr = w >> 1, wc = w & 1;
  const int laneoff = (lg >> 1) * 256 + (lg & 1) * 128 + lr * 4;

  const unsigned short* Ab = Ap + (size_t)(((o0 >> 4) + wr * 4) * 32) * 256 + laneoff;
  const unsigned short* Bb = Bp + (size_t)bz * 524288
      + (size_t)(((t0 >> 4) + wc * 4) * 32) * 256 + laneoff;

  f32x4 acc[4][4];
  #pragma unroll
  for (int m = 0; m < 4; m++)
    #pragma unroll
    for (int n = 0; n < 4; n++) acc[m][n] = f32x4{0.f, 0.f, 0.f, 0.f};

  #pragma unroll 2
  for (int kb = 0; kb < 32; kb += 2) {
    bf16x8 af[4], bf[4];
    #pragma unroll
    for (int m = 0; m < 4; m++) {
      const unsigned short* p = Ab + (m * 32 + kb) * 256;
      af[m] = cat8(*reinterpret_cast<const s16x4*>(p),
                   *reinterpret_cast<const s16x4*>(p + 64));
    }
    #pragma unroll
    for (int n = 0; n < 4; n++) {
      const unsigned short* p = Bb + (n * 32 + kb) * 256;
      bf[n] = cat8(*reinterpret_cast<const s16x4*>(p),
                   *reinterpret_cast<const s16x4*>(p + 64));
    }
    #pragma unroll
    for (int n = 0; n < 4; n++)
      #pragma unroll
      for (int m = 0; m < 4; m++)
        acc[m][n] = __builtin_amdgcn_mfma_f32_16x16x32_bf16(af[m], bf[n], acc[m][n], 0, 0, 0);
  }

  if (MODE == 0) {
    const int a = (o0 >> 6) + wr;              // 64-ch block, 0..23
    float bi[4][4];
    #pragma unroll
    for (int m = 0; m < 4; m++)
      #pragma unroll
      for (int r = 0; r < 4; r++)
        bi[m][r] = bias[a * 64 + m * 16 + lg * 4 + r];
    const int head = a / 3, part = a - head * 3;
    const size_t bho = ((size_t)bz * NHEAD + head) << 16;
    if (part < 2) {
      unsigned short* dst = (part == 0 ? oq : ok) + bho;
      #pragma unroll
      for (int n = 0; n < 4; n++) {
        const int rt4 = ((t0 >> 4) + wc * 4 + n) * 4;
        #pragma unroll
        for (int m = 0; m < 4; m++) {
          ushort4 st;
          st.x = f2us(acc[m][n][0] + bi[m][0]);
          st.y = f2us(acc[m][n][1] + bi[m][1]);
          st.z = f2us(acc[m][n][2] + bi[m][2]);
          st.w = f2us(acc[m][n][3] + bi[m][3]);
          *reinterpret_cast<ushort4*>(&dst[((size_t)(rt4 + m) << 8) + lg * 64 + lr * 4]) = st;
        }
      }
    } else {
      unsigned short* dst = ov + bho;
      const int vsub = (lr >> 2) * 64 + (lr & 3);
      #pragma unroll
      for (int m = 0; m < 4; m++)
        #pragma unroll
        for (int n = 0; n < 4; n++) {
          const int kt = (t0 >> 4) + wc * 4 + n;
          unsigned short* q = &dst[((size_t)(m * 64 + kt) << 8) + vsub];
          #pragma unroll
          for (int r = 0; r < 4; r++)
            q[(lg * 4 + r) * 4] = f2us(acc[m][n][r] + bi[m][r]);
        }
    }
  } else {
    #pragma unroll
    for (int m = 0; m < 4; m++)
      #pragma unroll
      for (int r = 0; r < 4; r++) {
        const int o = o0 + wr * 64 + m * 16 + lg * 4 + r;
        const float bv = bias[o];
        const size_t rowbase = ((size_t)bz * O + o) * TTT + t0 + wc * 64 + lr;
        #pragma unroll
        for (int n = 0; n < 4; n++) {
          const size_t idx = rowbase + n * 16;
          of[idx] = acc[m][n][r] + bv + resid[idx];
        }
      }
  }
}

// ---------------- packed-operand flash attention (no barriers) ----------------
__global__ __launch_bounds__(256) void attn_p(
    const unsigned short* __restrict__ qP,
    const unsigned short* __restrict__ kP,
    const unsigned short* __restrict__ vP,
    unsigned short* __restrict__ avP)
{
  const int bh = blockIdx.y;
  const int b = bh >> 3, hh = bh & 7;
  const int t0 = blockIdx.x << 6;
  const int tid = threadIdx.x;
  const int lane = tid & 63, w = tid >> 6;
  const int lg = lane >> 4, lr = lane & 15;
  const int laneoff = (lg >> 1) * 256 + (lg & 1) * 128 + lr * 4;

  __shared__ __align__(16) unsigned short pS[4][16][72];

  const unsigned short* Qb = qP + ((size_t)bh << 16) + laneoff;
  const unsigned short* Kb = kP + ((size_t)bh << 16) + laneoff;
  const unsigned short* Vb = vP + ((size_t)bh << 16) + laneoff;

  bf16x8 aq[2];
  {
    const unsigned short* qa = Qb + ((t0 >> 2) + w * 4) * 256;
    aq[0] = cat8(*reinterpret_cast<const s16x4*>(qa),
                 *reinterpret_cast<const s16x4*>(qa + 64));
    aq[1] = cat8(*reinterpret_cast<const s16x4*>(qa + 512),
                 *reinterpret_cast<const s16x4*>(qa + 512 + 64));
  }

  f32x4 opv[4];
  #pragma unroll
  for (int cn = 0; cn < 4; cn++) opv[cn] = f32x4{0.f, 0.f, 0.f, 0.f};
  float mrow[4] = {-1e30f, -1e30f, -1e30f, -1e30f};
  float lrow[4] = {0.f, 0.f, 0.f, 0.f};

  // K frags for tile 0
  bf16x8 kf[4][2];
  #pragma unroll
  for (int sn = 0; sn < 4; sn++)
    #pragma unroll
    for (int k2 = 0; k2 < 2; k2++) {
      const unsigned short* p = Kb + (sn * 4 + k2 * 2) * 256;
      kf[sn][k2] = cat8(*reinterpret_cast<const s16x4*>(p),
                        *reinterpret_cast<const s16x4*>(p + 64));
    }

  for (int sbi = 0; sbi < 16; sbi++) {
    const int sb = sbi << 6;

    // QK^T
    f32x4 sc[4];
    #pragma unroll
    for (int sn = 0; sn < 4; sn++) {
      f32x4 t = __builtin_amdgcn_mfma_f32_16x16x32_bf16(aq[0], kf[sn][0], f32x4{0.f, 0.f, 0.f, 0.f}, 0, 0, 0);
      sc[sn] = __builtin_amdgcn_mfma_f32_16x16x32_bf16(aq[1], kf[sn][1], t, 0, 0, 0);
    }

    // prefetch next tile's K into kf (wraps to 0 on last iter; harmless)
    const int sbn = (sbi < 15) ? (sb + 64) : 0;
    #pragma unroll
    for (int sn = 0; sn < 4; sn++)
      #pragma unroll
      for (int k2 = 0; k2 < 2; k2++) {
        const unsigned short* p = Kb + ((sbn >> 2) + sn * 4 + k2 * 2) * 256;
        kf[sn][k2] = cat8(*reinterpret_cast<const s16x4*>(p),
                          *reinterpret_cast<const s16x4*>(p + 64));
      }

    // V frags (packed row=c, k=s)
    bf16x8 bv[4][2];
    #pragma unroll
    for (int cn = 0; cn < 4; cn++)
      #pragma unroll
      for (int k2 = 0; k2 < 2; k2++) {
        const unsigned short* p = Vb + (cn * 64 + (sb >> 4) + k2 * 2) * 256;
        bv[cn][k2] = cat8(*reinterpret_cast<const s16x4*>(p),
                          *reinterpret_cast<const s16x4*>(p + 64));
      }

    // online softmax
    float pv[4][4];
    #pragma unroll
    for (int sn = 0; sn < 4; sn++)
      #pragma unroll
      for (int r = 0; r < 4; r++) pv[sn][r] = sc[sn][r] * 0.125f;

    float rescale[4];
    #pragma unroll
    for (int r = 0; r < 4; r++) {
      float mx = fmaxf(fmaxf(pv[0][r], pv[1][r]), fmaxf(pv[2][r], pv[3][r]));
      mx = fmaxf(mx, __shfl_xor(mx, 1));
      mx = fmaxf(mx, __shfl_xor(mx, 2));
      mx = fmaxf(mx, __shfl_xor(mx, 4));
      mx = fmaxf(mx, __shfl_xor(mx, 8));
      const float mn = fmaxf(mrow[r], mx);
      rescale[r] = __expf(mrow[r] - mn);
      mrow[r] = mn;
      float rs = 0.f;
      #pragma unroll
      for (int sn = 0; sn < 4; sn++) {
        pv[sn][r] = __expf(pv[sn][r] - mn);
        rs += pv[sn][r];
      }
      lrow[r] = lrow[r] * rescale[r] + rs;
    }
    #pragma unroll
    for (int cn = 0; cn < 4; cn++)
      #pragma unroll
      for (int r = 0; r < 4; r++) opv[cn][r] *= rescale[r];

    // P -> wave-private LDS (no barrier), read back as A-frag
    #pragma unroll
    for (int sn = 0; sn < 4; sn++)
      #pragma unroll
      for (int r = 0; r < 4; r++)
        pS[w][lg * 4 + r][sn * 16 + lr] = f2us(pv[sn][r]);

    const bf16x8 ap0 = *reinterpret_cast<const bf16x8*>(&pS[w][lr][lg * 8]);
    const bf16x8 ap1 = *reinterpret_cast<const bf16x8*>(&pS[w][lr][lg * 8 + 32]);
    #pragma unroll
    for (int cn = 0; cn < 4; cn++) {
      opv[cn] = __builtin_amdgcn_mfma_f32_16x16x32_bf16(ap0, bv[cn][0], opv[cn], 0, 0, 0);
      opv[cn] = __builtin_amdgcn_mfma_f32_16x16x32_bf16(ap1, bv[cn][1], opv[cn], 0, 0, 0);
    }
  }

  float inv[4];
  #pragma unroll
  for (int r = 0; r < 4; r++) {
    float v = lrow[r];
    v += __shfl_xor(v, 1);
    v += __shfl_xor(v, 2);
    v += __shfl_xor(v, 4);
    v += __shfl_xor(v, 8);
    inv[r] = 1.f / v;
  }

  // avT packed (row=t, k=c over full 512): subtile (rt, kt=hh*4+cn)
  const int rt = (t0 >> 4) + w;
  unsigned short* dst = avP + (size_t)b * 524288 + (lr >> 2) * 64 + (lr & 3);
  #pragma unroll
  for (int cn = 0; cn < 4; cn++) {
    unsigned short* q = dst + ((size_t)(rt * 32 + hh * 4 + cn) << 8);
    #pragma unroll
    for (int r = 0; r < 4; r++)
      q[(lg * 4 + r) * 4] = f2us(opv[cn][r] * inv[r]);
  }
}

extern "C" void kernel_launch(void* const* d_in, const int* in_sizes, int n_in,
                              void* d_out, int out_size, void* d_ws, size_t ws_size,
                              hipStream_t stream) {
  const float* x      = (const float*)d_in[0];
  const float* gn_w   = (const float*)d_in[1];
  const float* gn_b   = (const float*)d_in[2];
  const float* qkv_w  = (const float*)d_in[3];
  const float* qkv_b  = (const float*)d_in[4];
  const float* proj_w = (const float*)d_in[5];
  const float* proj_b = (const float*)d_in[6];
  float* out = (float*)d_out;

  const size_t HT = (size_t)BBB * TTT * CCH;           // 4M elems
  const size_t QK = (size_t)BBB * NHEAD * TTT * CHD;   // 4M elems
  unsigned short* hP  = (unsigned short*)d_ws;         // packed H, 8 MB
  unsigned short* vP  = hP + HT;                       // packed V, 8 MB
  unsigned short* avP = vP + QK;                       // packed avT, 8 MB
  unsigned short* wq  = avP + HT;                      // packed qkv_w, 1.5 MB
  unsigned short* wp  = wq + (size_t)O_QKV * CCH;      // packed proj_w, 0.5 MB
  // Q/K packed live in d_out (16 MB): fully rewritten each launch, consumed
  // by attn before proj overwrites d_out (stream-ordered).
  unsigned short* qPd = (unsigned short*)d_out;
  unsigned short* kPd = qPd + QK;

  wpack_kernel<<<dim3(768), 256, 0, stream>>>(qkv_w, wq, O_QKV * CCH / 4);
  wpack_kernel<<<dim3(256), 256, 0, stream>>>(proj_w, wp, CCH * CCH / 4);
  gn_kernel<<<dim3(BBB * NGRP), 256, 0, stream>>>(x, gn_w, gn_b, hP);
  gemm_p<0><<<dim3(TTT / 128, O_QKV / 128, BBB), 256, 0, stream>>>(
      wq, hP, qkv_b, nullptr, qPd, kPd, vP, nullptr, O_QKV);
  attn_p<<<dim3(TTT / 64, BBB * NHEAD), 256, 0, stream>>>(qPd, kPd, vP, avP);
  gemm_p<1><<<dim3(TTT / 128, CCH / 128, BBB), 256, 0, stream>>>(
      wp, avP, proj_b, x, nullptr, nullptr, nullptr, out, CCH);
}

// Round 7
// 130.228 us; speedup vs baseline: 1.7739x; 1.0060x over previous
//
#include <hip/hip_runtime.h>
#include <hip/hip_bf16.h>

#define CCH 512
#define TTT 1024
#define BBB 8
#define NGRP 32
#define CPG 16
#define NHEAD 8
#define CHD 64
#define O_QKV 1536

typedef __attribute__((ext_vector_type(8))) short bf16x8;
typedef __attribute__((ext_vector_type(4))) short s16x4;
typedef __attribute__((ext_vector_type(4))) float f32x4;

__device__ __forceinline__ float us2f(unsigned short u) {
  union { unsigned int i; float f; } p; p.i = ((unsigned int)u) << 16; return p.f;
}
__device__ __forceinline__ unsigned short f2us(float f) {
  __hip_bfloat16 b = __float2bfloat16(f);
  return *reinterpret_cast<unsigned short*>(&b);
}
__device__ __forceinline__ bf16x8 cat8(s16x4 a, s16x4 b) {
  bf16x8 r;
  r[0] = a[0]; r[1] = a[1]; r[2] = a[2]; r[3] = a[3];
  r[4] = b[0]; r[5] = b[1]; r[6] = b[2]; r[7] = b[3];
  return r;
}

// Packed layout for a logical [R rows][K cols] bf16 matrix consumed as MFMA frags:
//   subtile (rt=row/16, kt=k/16) base = (rt*(K/16)+kt)*256
//   within: ((k%16)/4)*64 + (row%16)*4 + (k%4)

// ---------------- W f32 -> packed bf16 (qkv_w then proj_w, one launch) ----------------
__global__ __launch_bounds__(256) void wpack_kernel(
    const float* __restrict__ wq, const float* __restrict__ wp,
    unsigned short* __restrict__ op, int nslot)
{
  const int s = blockIdx.x * 256 + threadIdx.x;   // one ushort4 slot
  if (s >= nslot) return;
  const int u = s & 63, sub = s >> 6;
  const int kt = sub & 31, rt = sub >> 5;         // K = 512 -> 32 kt
  const int lg = u >> 4, lr = u & 15;
  const int row = rt * 16 + lr;
  const float* src = (row < O_QKV) ? &wq[(size_t)row * CCH]
                                   : &wp[(size_t)(row - O_QKV) * CCH];
  float4 v = *reinterpret_cast<const float4*>(&src[kt * 16 + lg * 4]);
  ushort4 r;
  r.x = f2us(v.x); r.y = f2us(v.y); r.z = f2us(v.z); r.w = f2us(v.w);
  reinterpret_cast<ushort4*>(op)[s] = r;
}

// ---------------- GroupNorm: f32 [b][c][t] -> packed H (row=t, k=c) ----------------
__global__ __launch_bounds__(256) void gn_kernel(
    const float* __restrict__ x,
    const float* __restrict__ gw,
    const float* __restrict__ gb,
    unsigned short* __restrict__ hP)
{
  const int bg = blockIdx.x;
  const int bb = bg >> 5, g = bg & 31;
  const size_t base = ((size_t)bb * CCH + (size_t)g * CPG) * TTT;
  const float4* xv = reinterpret_cast<const float4*>(x + base);
  const int tid = threadIdx.x;

  float s = 0.f, q = 0.f;
  for (int i = tid; i < 4096; i += 256) {
    float4 u = xv[i];
    s += (u.x + u.y) + (u.z + u.w);
    q += u.x * u.x + u.y * u.y + u.z * u.z + u.w * u.w;
  }
  #pragma unroll
  for (int off = 32; off > 0; off >>= 1) {
    s += __shfl_down(s, off);
    q += __shfl_down(q, off);
  }
  __shared__ float red[10];
  const int wid = tid >> 6, lane = tid & 63;
  if (lane == 0) { red[wid] = s; red[4 + wid] = q; }
  __syncthreads();
  if (tid == 0) {
    float S = red[0] + red[1] + red[2] + red[3];
    float Q = red[4] + red[5] + red[6] + red[7];
    float mu = S * (1.f / 16384.f);
    float var = Q * (1.f / 16384.f) - mu * mu;
    red[8] = mu;
    red[9] = rsqrtf(var + 1e-5f);
  }
  __syncthreads();
  const float mu = red[8], rstd = red[9];
  float wsc[16], wbs[16];
  #pragma unroll
  for (int cc = 0; cc < 16; cc++) {
    wsc[cc] = gw[g * CPG + cc] * rstd;
    wbs[cc] = gb[g * CPG + cc] - mu * wsc[cc];
  }
  for (int tt = tid; tt < TTT; tt += 256) {
    float v[16];
    #pragma unroll
    for (int cc = 0; cc < 16; cc++)
      v[cc] = fmaf(x[base + (size_t)cc * TTT + tt], wsc[cc], wbs[cc]);
    unsigned short* dst = &hP[(size_t)bb * 524288 + ((size_t)((tt >> 4) * 32 + g)) * 256 + (tt & 15) * 4];
    #pragma unroll
    for (int l2 = 0; l2 < 4; l2++) {
      ushort4 st;
      st.x = f2us(v[l2 * 4 + 0]);
      st.y = f2us(v[l2 * 4 + 1]);
      st.z = f2us(v[l2 * 4 + 2]);
      st.w = f2us(v[l2 * 4 + 3]);
      *reinterpret_cast<ushort4*>(&dst[l2 * 64]) = st;
    }
  }
}

// ---------------- LDS-free packed MFMA GEMM (unchanged from R6) ----------------
template<int MODE>
__global__ __launch_bounds__(256) void gemm_p(
    const unsigned short* __restrict__ Ap,    // packed W
    const unsigned short* __restrict__ Bp,    // packed H/avT per b
    const float* __restrict__ bias,
    const float* __restrict__ resid,
    unsigned short* __restrict__ oq,
    unsigned short* __restrict__ ok,
    unsigned short* __restrict__ ov,
    float* __restrict__ of,
    const int O)
{
  const int tid = threadIdx.x;
  const int bz = blockIdx.z, o0 = blockIdx.y << 7, t0 = blockIdx.x << 7;
  const int lane = tid & 63, w = tid >> 6;
  const int lg = lane >> 4, lr = lane & 15;
  const int wr = w >> 1, wc = w & 1;
  const int laneoff = (lg >> 1) * 256 + (lg & 1) * 128 + lr * 4;

  const unsigned short* Ab = Ap + (size_t)(((o0 >> 4) + wr * 4) * 32) * 256 + laneoff;
  const unsigned short* Bb = Bp + (size_t)bz * 524288
      + (size_t)(((t0 >> 4) + wc * 4) * 32) * 256 + laneoff;

  f32x4 acc[4][4];
  #pragma unroll
  for (int m = 0; m < 4; m++)
    #pragma unroll
    for (int n = 0; n < 4; n++) acc[m][n] = f32x4{0.f, 0.f, 0.f, 0.f};

  #pragma unroll 2
  for (int kb = 0; kb < 32; kb += 2) {
    bf16x8 af[4], bf[4];
    #pragma unroll
    for (int m = 0; m < 4; m++) {
      const unsigned short* p = Ab + (m * 32 + kb) * 256;
      af[m] = cat8(*reinterpret_cast<const s16x4*>(p),
                   *reinterpret_cast<const s16x4*>(p + 64));
    }
    #pragma unroll
    for (int n = 0; n < 4; n++) {
      const unsigned short* p = Bb + (n * 32 + kb) * 256;
      bf[n] = cat8(*reinterpret_cast<const s16x4*>(p),
                   *reinterpret_cast<const s16x4*>(p + 64));
    }
    #pragma unroll
    for (int n = 0; n < 4; n++)
      #pragma unroll
      for (int m = 0; m < 4; m++)
        acc[m][n] = __builtin_amdgcn_mfma_f32_16x16x32_bf16(af[m], bf[n], acc[m][n], 0, 0, 0);
  }

  if (MODE == 0) {
    const int a = (o0 >> 6) + wr;              // 64-ch block, 0..23
    float bi[4][4];
    #pragma unroll
    for (int m = 0; m < 4; m++)
      #pragma unroll
      for (int r = 0; r < 4; r++)
        bi[m][r] = bias[a * 64 + m * 16 + lg * 4 + r];
    const int head = a / 3, part = a - head * 3;
    const size_t bho = ((size_t)bz * NHEAD + head) << 16;
    if (part < 2) {
      unsigned short* dst = (part == 0 ? oq : ok) + bho;
      #pragma unroll
      for (int n = 0; n < 4; n++) {
        const int rt4 = ((t0 >> 4) + wc * 4 + n) * 4;
        #pragma unroll
        for (int m = 0; m < 4; m++) {
          ushort4 st;
          st.x = f2us(acc[m][n][0] + bi[m][0]);
          st.y = f2us(acc[m][n][1] + bi[m][1]);
          st.z = f2us(acc[m][n][2] + bi[m][2]);
          st.w = f2us(acc[m][n][3] + bi[m][3]);
          *reinterpret_cast<ushort4*>(&dst[((size_t)(rt4 + m) << 8) + lg * 64 + lr * 4]) = st;
        }
      }
    } else {
      unsigned short* dst = ov + bho;
      const int vsub = (lr >> 2) * 64 + (lr & 3);
      #pragma unroll
      for (int m = 0; m < 4; m++)
        #pragma unroll
        for (int n = 0; n < 4; n++) {
          const int kt = (t0 >> 4) + wc * 4 + n;
          unsigned short* q = &dst[((size_t)(m * 64 + kt) << 8) + vsub];
          #pragma unroll
          for (int r = 0; r < 4; r++)
            q[(lg * 4 + r) * 4] = f2us(acc[m][n][r] + bi[m][r]);
        }
    }
  } else {
    #pragma unroll
    for (int m = 0; m < 4; m++)
      #pragma unroll
      for (int r = 0; r < 4; r++) {
        const int o = o0 + wr * 64 + m * 16 + lg * 4 + r;
        const float bv = bias[o];
        const size_t rowbase = ((size_t)bz * O + o) * TTT + t0 + wc * 64 + lr;
        #pragma unroll
        for (int n = 0; n < 4; n++) {
          const size_t idx = rowbase + n * 16;
          of[idx] = acc[m][n][r] + bv + resid[idx];
        }
      }
  }
}

// ---------------- packed-operand flash attention, 8 waves/block ----------------
// XCD-bijective bid remap: all 8 t-blocks of one bh share bid%8 (same XCD L2).
// exp2-domain softmax (scores scaled by 0.125*log2e; m/rescale in log2 units).
__global__ __launch_bounds__(512) void attn_p(
    const unsigned short* __restrict__ qP,
    const unsigned short* __restrict__ kP,
    const unsigned short* __restrict__ vP,
    unsigned short* __restrict__ avP)
{
  const int bid = blockIdx.x;                    // 0..511
  const int bh = (bid & 7) * 8 + (bid >> 6);     // bijective
  const int t0 = ((bid >> 3) & 7) << 7;          // 8 t-blocks of 128 queries
  const int b = bh >> 3, hh = bh & 7;
  const int tid = threadIdx.x;
  const int lane = tid & 63, w = tid >> 6;       // w = 0..7
  const int lg = lane >> 4, lr = lane & 15;
  const int laneoff = (lg >> 1) * 256 + (lg & 1) * 128 + lr * 4;

  __shared__ __align__(16) unsigned short pS[8][16][72];

  const unsigned short* Qb = qP + ((size_t)bh << 16) + laneoff;
  const unsigned short* Kb = kP + ((size_t)bh << 16) + laneoff;
  const unsigned short* Vb = vP + ((size_t)bh << 16) + laneoff;

  bf16x8 aq[2];
  {
    const unsigned short* qa = Qb + ((t0 >> 2) + w * 4) * 256;
    aq[0] = cat8(*reinterpret_cast<const s16x4*>(qa),
                 *reinterpret_cast<const s16x4*>(qa + 64));
    aq[1] = cat8(*reinterpret_cast<const s16x4*>(qa + 512),
                 *reinterpret_cast<const s16x4*>(qa + 512 + 64));
  }

  f32x4 opv[4];
  #pragma unroll
  for (int cn = 0; cn < 4; cn++) opv[cn] = f32x4{0.f, 0.f, 0.f, 0.f};
  float mrow[4] = {-1e30f, -1e30f, -1e30f, -1e30f};
  float lrow[4] = {0.f, 0.f, 0.f, 0.f};
  const float SC2 = 0.125f * 1.44269504f;        // fold 1/8 scale + log2(e)

  // K frags for tile 0
  bf16x8 kf[4][2];
  #pragma unroll
  for (int sn = 0; sn < 4; sn++)
    #pragma unroll
    for (int k2 = 0; k2 < 2; k2++) {
      const unsigned short* p = Kb + (sn * 4 + k2 * 2) * 256;
      kf[sn][k2] = cat8(*reinterpret_cast<const s16x4*>(p),
                        *reinterpret_cast<const s16x4*>(p + 64));
    }

  for (int sbi = 0; sbi < 16; sbi++) {
    const int sb = sbi << 6;

    // QK^T
    f32x4 sc[4];
    #pragma unroll
    for (int sn = 0; sn < 4; sn++) {
      f32x4 t = __builtin_amdgcn_mfma_f32_16x16x32_bf16(aq[0], kf[sn][0], f32x4{0.f, 0.f, 0.f, 0.f}, 0, 0, 0);
      sc[sn] = __builtin_amdgcn_mfma_f32_16x16x32_bf16(aq[1], kf[sn][1], t, 0, 0, 0);
    }

    // prefetch next tile's K (wraps on last iter; harmless)
    const int sbn = (sbi < 15) ? (sb + 64) : 0;
    #pragma unroll
    for (int sn = 0; sn < 4; sn++)
      #pragma unroll
      for (int k2 = 0; k2 < 2; k2++) {
        const unsigned short* p = Kb + ((sbn >> 2) + sn * 4 + k2 * 2) * 256;
        kf[sn][k2] = cat8(*reinterpret_cast<const s16x4*>(p),
                          *reinterpret_cast<const s16x4*>(p + 64));
      }

    // V frags (packed row=c, k=s)
    bf16x8 bv[4][2];
    #pragma unroll
    for (int cn = 0; cn < 4; cn++)
      #pragma unroll
      for (int k2 = 0; k2 < 2; k2++) {
        const unsigned short* p = Vb + (cn * 64 + (sb >> 4) + k2 * 2) * 256;
        bv[cn][k2] = cat8(*reinterpret_cast<const s16x4*>(p),
                          *reinterpret_cast<const s16x4*>(p + 64));
      }

    // online softmax in exp2 domain
    float pv[4][4];
    #pragma unroll
    for (int sn = 0; sn < 4; sn++)
      #pragma unroll
      for (int r = 0; r < 4; r++) pv[sn][r] = sc[sn][r] * SC2;

    float rescale[4];
    #pragma unroll
    for (int r = 0; r < 4; r++) {
      float mx = fmaxf(fmaxf(pv[0][r], pv[1][r]), fmaxf(pv[2][r], pv[3][r]));
      mx = fmaxf(mx, __shfl_xor(mx, 1));
      mx = fmaxf(mx, __shfl_xor(mx, 2));
      mx = fmaxf(mx, __shfl_xor(mx, 4));
      mx = fmaxf(mx, __shfl_xor(mx, 8));
      const float mn = fmaxf(mrow[r], mx);
      rescale[r] = exp2f(mrow[r] - mn);
      mrow[r] = mn;
      float rs = 0.f;
      #pragma unroll
      for (int sn = 0; sn < 4; sn++) {
        pv[sn][r] = exp2f(pv[sn][r] - mn);
        rs += pv[sn][r];
      }
      lrow[r] = lrow[r] * rescale[r] + rs;
    }
    #pragma unroll
    for (int cn = 0; cn < 4; cn++)
      #pragma unroll
      for (int r = 0; r < 4; r++) opv[cn][r] *= rescale[r];

    // P -> wave-private LDS (no barrier), read back as A-frag
    #pragma unroll
    for (int sn = 0; sn < 4; sn++)
      #pragma unroll
      for (int r = 0; r < 4; r++)
        pS[w][lg * 4 + r][sn * 16 + lr] = f2us(pv[sn][r]);

    const bf16x8 ap0 = *reinterpret_cast<const bf16x8*>(&pS[w][lr][lg * 8]);
    const bf16x8 ap1 = *reinterpret_cast<const bf16x8*>(&pS[w][lr][lg * 8 + 32]);
    #pragma unroll
    for (int cn = 0; cn < 4; cn++) {
      opv[cn] = __builtin_amdgcn_mfma_f32_16x16x32_bf16(ap0, bv[cn][0], opv[cn], 0, 0, 0);
      opv[cn] = __builtin_amdgcn_mfma_f32_16x16x32_bf16(ap1, bv[cn][1], opv[cn], 0, 0, 0);
    }
  }

  float inv[4];
  #pragma unroll
  for (int r = 0; r < 4; r++) {
    float v = lrow[r];
    v += __shfl_xor(v, 1);
    v += __shfl_xor(v, 2);
    v += __shfl_xor(v, 4);
    v += __shfl_xor(v, 8);
    inv[r] = 1.f / v;
  }

  // avT packed (row=t, k=c over full 512): subtile (rt, kt=hh*4+cn)
  const int rt = (t0 >> 4) + w;
  unsigned short* dst = avP + (size_t)b * 524288 + (lr >> 2) * 64 + (lr & 3);
  #pragma unroll
  for (int cn = 0; cn < 4; cn++) {
    unsigned short* q = dst + ((size_t)(rt * 32 + hh * 4 + cn) << 8);
    #pragma unroll
    for (int r = 0; r < 4; r++)
      q[(lg * 4 + r) * 4] = f2us(opv[cn][r] * inv[r]);
  }
}

extern "C" void kernel_launch(void* const* d_in, const int* in_sizes, int n_in,
                              void* d_out, int out_size, void* d_ws, size_t ws_size,
                              hipStream_t stream) {
  const float* x      = (const float*)d_in[0];
  const float* gn_w   = (const float*)d_in[1];
  const float* gn_b   = (const float*)d_in[2];
  const float* qkv_w  = (const float*)d_in[3];
  const float* qkv_b  = (const float*)d_in[4];
  const float* proj_w = (const float*)d_in[5];
  const float* proj_b = (const float*)d_in[6];
  float* out = (float*)d_out;

  const size_t HT = (size_t)BBB * TTT * CCH;           // 4M elems
  const size_t QK = (size_t)BBB * NHEAD * TTT * CHD;   // 4M elems
  unsigned short* hP  = (unsigned short*)d_ws;         // packed H, 8 MB
  unsigned short* vP  = hP + HT;                       // packed V, 8 MB
  unsigned short* avP = vP + QK;                       // packed avT, 8 MB
  unsigned short* wq  = avP + HT;                      // packed qkv_w, 1.5 MB
  // wp contiguous after wq (wpack writes both in one pass)
  unsigned short* wp  = wq + (size_t)O_QKV * CCH;      // packed proj_w, 0.5 MB
  // Q/K packed live in d_out (16 MB): fully rewritten each launch, consumed
  // by attn before proj overwrites d_out (stream-ordered).
  unsigned short* qPd = (unsigned short*)d_out;
  unsigned short* kPd = qPd + QK;

  const int nslot = (O_QKV + CCH) * CCH / 4;           // 262144
  wpack_kernel<<<dim3(nslot / 256), 256, 0, stream>>>(qkv_w, proj_w, wq, nslot);
  gn_kernel<<<dim3(BBB * NGRP), 256, 0, stream>>>(x, gn_w, gn_b, hP);
  gemm_p<0><<<dim3(TTT / 128, O_QKV / 128, BBB), 256, 0, stream>>>(
      wq, hP, qkv_b, nullptr, qPd, kPd, vP, nullptr, O_QKV);
  attn_p<<<dim3(512), 512, 0, stream>>>(qPd, kPd, vP, avP);
  gemm_p<1><<<dim3(TTT / 128, CCH / 128, BBB), 256, 0, stream>>>(
      wp, avP, proj_b, x, nullptr, nullptr, nullptr, out, CCH);
}

// Round 8
// 126.603 us; speedup vs baseline: 1.8247x; 1.0286x over previous
//
#include <hip/hip_runtime.h>
#include <hip/hip_bf16.h>

#define CCH 512
#define TTT 1024
#define BBB 8
#define NGRP 32
#define CPG 16
#define NHEAD 8
#define CHD 64
#define O_QKV 1536

typedef __attribute__((ext_vector_type(8))) short bf16x8;
typedef __attribute__((ext_vector_type(4))) short s16x4;
typedef __attribute__((ext_vector_type(4))) float f32x4;

__device__ __forceinline__ float us2f(unsigned short u) {
  union { unsigned int i; float f; } p; p.i = ((unsigned int)u) << 16; return p.f;
}
__device__ __forceinline__ unsigned short f2us(float f) {
  __hip_bfloat16 b = __float2bfloat16(f);
  return *reinterpret_cast<unsigned short*>(&b);
}
__device__ __forceinline__ bf16x8 cat8(s16x4 a, s16x4 b) {
  bf16x8 r;
  r[0] = a[0]; r[1] = a[1]; r[2] = a[2]; r[3] = a[3];
  r[4] = b[0]; r[5] = b[1]; r[6] = b[2]; r[7] = b[3];
  return r;
}
__device__ __forceinline__ float hmax4(f32x4 v) {
  return fmaxf(fmaxf(v[0], v[1]), fmaxf(v[2], v[3]));
}

// Packed layout for a logical [R rows][K cols] bf16 matrix consumed as MFMA frags:
//   subtile (rt=row/16, kt=k/16) base = (rt*(K/16)+kt)*256
//   within: ((k%16)/4)*64 + (row%16)*4 + (k%4)

// ---------------- W f32 -> packed bf16 (qkv_w then proj_w, one launch) ----------------
__global__ __launch_bounds__(256) void wpack_kernel(
    const float* __restrict__ wq, const float* __restrict__ wp,
    unsigned short* __restrict__ op, int nslot)
{
  const int s = blockIdx.x * 256 + threadIdx.x;   // one ushort4 slot
  if (s >= nslot) return;
  const int u = s & 63, sub = s >> 6;
  const int kt = sub & 31, rt = sub >> 5;         // K = 512 -> 32 kt
  const int lg = u >> 4, lr = u & 15;
  const int row = rt * 16 + lr;
  const float* src = (row < O_QKV) ? &wq[(size_t)row * CCH]
                                   : &wp[(size_t)(row - O_QKV) * CCH];
  float4 v = *reinterpret_cast<const float4*>(&src[kt * 16 + lg * 4]);
  ushort4 r;
  r.x = f2us(v.x); r.y = f2us(v.y); r.z = f2us(v.z); r.w = f2us(v.w);
  reinterpret_cast<ushort4*>(op)[s] = r;
}

// ---------------- GroupNorm: f32 [b][c][t] -> packed H (row=t, k=c) ----------------
// Pass-2 reads x from a 64 KB LDS stage (bit-identical) instead of global.
__global__ __launch_bounds__(256) void gn_kernel(
    const float* __restrict__ x,
    const float* __restrict__ gw,
    const float* __restrict__ gb,
    unsigned short* __restrict__ hP)
{
  __shared__ __align__(16) float xs[16][1028];   // pad 1028 -> pass2 conflict-free
  const int bg = blockIdx.x;
  const int bb = bg >> 5, g = bg & 31;
  const size_t base = ((size_t)bb * CCH + (size_t)g * CPG) * TTT;
  const float4* xv = reinterpret_cast<const float4*>(x + base);
  const int tid = threadIdx.x;

  float s = 0.f, q = 0.f;
  for (int i = tid; i < 4096; i += 256) {
    float4 u = xv[i];
    const int c = i >> 8, t4 = (i & 255) << 2;
    *reinterpret_cast<float4*>(&xs[c][t4]) = u;
    s += (u.x + u.y) + (u.z + u.w);
    q += u.x * u.x + u.y * u.y + u.z * u.z + u.w * u.w;
  }
  #pragma unroll
  for (int off = 32; off > 0; off >>= 1) {
    s += __shfl_down(s, off);
    q += __shfl_down(q, off);
  }
  __shared__ float red[10];
  const int wid = tid >> 6, lane = tid & 63;
  if (lane == 0) { red[wid] = s; red[4 + wid] = q; }
  __syncthreads();
  if (tid == 0) {
    float S = red[0] + red[1] + red[2] + red[3];
    float Q = red[4] + red[5] + red[6] + red[7];
    float mu = S * (1.f / 16384.f);
    float var = Q * (1.f / 16384.f) - mu * mu;
    red[8] = mu;
    red[9] = rsqrtf(var + 1e-5f);
  }
  __syncthreads();
  const float mu = red[8], rstd = red[9];
  float wsc[16], wbs[16];
  #pragma unroll
  for (int cc = 0; cc < 16; cc++) {
    wsc[cc] = gw[g * CPG + cc] * rstd;
    wbs[cc] = gb[g * CPG + cc] - mu * wsc[cc];
  }
  for (int tt = tid; tt < 1024; tt += 256) {
    float v[16];
    #pragma unroll
    for (int cc = 0; cc < 16; cc++)
      v[cc] = fmaf(xs[cc][tt], wsc[cc], wbs[cc]);
    unsigned short* dst = &hP[(size_t)bb * 524288 + ((size_t)((tt >> 4) * 32 + g)) * 256 + (tt & 15) * 4];
    #pragma unroll
    for (int l2 = 0; l2 < 4; l2++) {
      ushort4 st;
      st.x = f2us(v[l2 * 4 + 0]);
      st.y = f2us(v[l2 * 4 + 1]);
      st.z = f2us(v[l2 * 4 + 2]);
      st.w = f2us(v[l2 * 4 + 3]);
      *reinterpret_cast<ushort4*>(&dst[l2 * 64]) = st;
    }
  }
}

// ---------------- LDS-free packed MFMA GEMM (unchanged from R7) ----------------
template<int MODE>
__global__ __launch_bounds__(256) void gemm_p(
    const unsigned short* __restrict__ Ap,    // packed W
    const unsigned short* __restrict__ Bp,    // packed H/avT per b
    const float* __restrict__ bias,
    const float* __restrict__ resid,
    unsigned short* __restrict__ oq,
    unsigned short* __restrict__ ok,
    unsigned short* __restrict__ ov,
    float* __restrict__ of,
    const int O)
{
  const int tid = threadIdx.x;
  const int bz = blockIdx.z, o0 = blockIdx.y << 7, t0 = blockIdx.x << 7;
  const int lane = tid & 63, w = tid >> 6;
  const int lg = lane >> 4, lr = lane & 15;
  const int wr = w >> 1, wc = w & 1;
  const int laneoff = (lg >> 1) * 256 + (lg & 1) * 128 + lr * 4;

  const unsigned short* Ab = Ap + (size_t)(((o0 >> 4) + wr * 4) * 32) * 256 + laneoff;
  const unsigned short* Bb = Bp + (size_t)bz * 524288
      + (size_t)(((t0 >> 4) + wc * 4) * 32) * 256 + laneoff;

  f32x4 acc[4][4];
  #pragma unroll
  for (int m = 0; m < 4; m++)
    #pragma unroll
    for (int n = 0; n < 4; n++) acc[m][n] = f32x4{0.f, 0.f, 0.f, 0.f};

  #pragma unroll 2
  for (int kb = 0; kb < 32; kb += 2) {
    bf16x8 af[4], bf[4];
    #pragma unroll
    for (int m = 0; m < 4; m++) {
      const unsigned short* p = Ab + (m * 32 + kb) * 256;
      af[m] = cat8(*reinterpret_cast<const s16x4*>(p),
                   *reinterpret_cast<const s16x4*>(p + 64));
    }
    #pragma unroll
    for (int n = 0; n < 4; n++) {
      const unsigned short* p = Bb + (n * 32 + kb) * 256;
      bf[n] = cat8(*reinterpret_cast<const s16x4*>(p),
                   *reinterpret_cast<const s16x4*>(p + 64));
    }
    #pragma unroll
    for (int n = 0; n < 4; n++)
      #pragma unroll
      for (int m = 0; m < 4; m++)
        acc[m][n] = __builtin_amdgcn_mfma_f32_16x16x32_bf16(af[m], bf[n], acc[m][n], 0, 0, 0);
  }

  if (MODE == 0) {
    const int a = (o0 >> 6) + wr;              // 64-ch block, 0..23
    float bi[4][4];
    #pragma unroll
    for (int m = 0; m < 4; m++)
      #pragma unroll
      for (int r = 0; r < 4; r++)
        bi[m][r] = bias[a * 64 + m * 16 + lg * 4 + r];
    const int head = a / 3, part = a - head * 3;
    const size_t bho = ((size_t)bz * NHEAD + head) << 16;
    if (part < 2) {
      unsigned short* dst = (part == 0 ? oq : ok) + bho;
      #pragma unroll
      for (int n = 0; n < 4; n++) {
        const int rt4 = ((t0 >> 4) + wc * 4 + n) * 4;
        #pragma unroll
        for (int m = 0; m < 4; m++) {
          ushort4 st;
          st.x = f2us(acc[m][n][0] + bi[m][0]);
          st.y = f2us(acc[m][n][1] + bi[m][1]);
          st.z = f2us(acc[m][n][2] + bi[m][2]);
          st.w = f2us(acc[m][n][3] + bi[m][3]);
          *reinterpret_cast<ushort4*>(&dst[((size_t)(rt4 + m) << 8) + lg * 64 + lr * 4]) = st;
        }
      }
    } else {
      unsigned short* dst = ov + bho;
      const int vsub = (lr >> 2) * 64 + (lr & 3);
      #pragma unroll
      for (int m = 0; m < 4; m++)
        #pragma unroll
        for (int n = 0; n < 4; n++) {
          const int kt = (t0 >> 4) + wc * 4 + n;
          unsigned short* q = &dst[((size_t)(m * 64 + kt) << 8) + vsub];
          #pragma unroll
          for (int r = 0; r < 4; r++)
            q[(lg * 4 + r) * 4] = f2us(acc[m][n][r] + bi[m][r]);
        }
    }
  } else {
    #pragma unroll
    for (int m = 0; m < 4; m++)
      #pragma unroll
      for (int r = 0; r < 4; r++) {
        const int o = o0 + wr * 64 + m * 16 + lg * 4 + r;
        const float bv = bias[o];
        const size_t rowbase = ((size_t)bz * O + o) * TTT + t0 + wc * 64 + lr;
        #pragma unroll
        for (int n = 0; n < 4; n++) {
          const size_t idx = rowbase + n * 16;
          of[idx] = acc[m][n][r] + bv + resid[idx];
        }
      }
  }
}

// ---------------- swapped-operand flash attention ----------------
// QK^T computed as mfma(K, Q) -> S[s][t], t = lane&15: softmax row is
// lane-local (15 in-reg fmax + 2 shuffles). PV as mfma(V, P) -> O[c][t].
// P round-trip: 4 ds_write_b64 + 2 ds_read_b128, XOR-8 s-block swizzle.
__global__ __launch_bounds__(512) void attn_p(
    const unsigned short* __restrict__ qP,
    const unsigned short* __restrict__ kP,
    const unsigned short* __restrict__ vP,
    unsigned short* __restrict__ avP)
{
  const int bid = blockIdx.x;                    // 0..511
  const int bh = (bid & 7) * 8 + (bid >> 6);     // XCD-bijective
  const int t0 = ((bid >> 3) & 7) << 7;          // 8 t-blocks of 128 queries
  const int b = bh >> 3, hh = bh & 7;
  const int tid = threadIdx.x;
  const int lane = tid & 63, w = tid >> 6;       // w = 0..7
  const int lg = lane >> 4, lr = lane & 15;
  const int laneoff = (lg >> 1) * 256 + (lg & 1) * 128 + lr * 4;

  __shared__ __align__(16) unsigned short pS[8][16][72];  // [w][t_local][s(+swz)]

  const unsigned short* Qb = qP + ((size_t)bh << 16) + laneoff;
  const unsigned short* Kb = kP + ((size_t)bh << 16) + laneoff;
  const unsigned short* Vb = vP + ((size_t)bh << 16) + laneoff;

  // Q B-frag (col=t, k=c) — loads unchanged
  bf16x8 aq[2];
  {
    const unsigned short* qa = Qb + ((t0 >> 2) + w * 4) * 256;
    aq[0] = cat8(*reinterpret_cast<const s16x4*>(qa),
                 *reinterpret_cast<const s16x4*>(qa + 64));
    aq[1] = cat8(*reinterpret_cast<const s16x4*>(qa + 512),
                 *reinterpret_cast<const s16x4*>(qa + 512 + 64));
  }

  f32x4 opv[4];
  #pragma unroll
  for (int cn = 0; cn < 4; cn++) opv[cn] = f32x4{0.f, 0.f, 0.f, 0.f};
  float mrow = -1e30f, lrow = 0.f;               // scalar per lane (one query)
  const float SC2 = 0.125f * 1.44269504f;        // 1/8 scale * log2(e)

  // K frags tile 0 (A-operand now; same addresses)
  bf16x8 kf[4][2];
  #pragma unroll
  for (int sn = 0; sn < 4; sn++)
    #pragma unroll
    for (int k2 = 0; k2 < 2; k2++) {
      const unsigned short* p = Kb + (sn * 4 + k2 * 2) * 256;
      kf[sn][k2] = cat8(*reinterpret_cast<const s16x4*>(p),
                        *reinterpret_cast<const s16x4*>(p + 64));
    }

  const int swz = lr & 8;                        // XOR-8 s-block swizzle key

  for (int sbi = 0; sbi < 16; sbi++) {
    const int sb = sbi << 6;

    // QK^T swapped: sc[sn][r] = S[s = sb + sn*16 + lg*4 + r][t = t0 + w*16 + lr]
    f32x4 sc[4];
    __builtin_amdgcn_s_setprio(1);
    #pragma unroll
    for (int sn = 0; sn < 4; sn++) {
      f32x4 t = __builtin_amdgcn_mfma_f32_16x16x32_bf16(kf[sn][0], aq[0], f32x4{0.f, 0.f, 0.f, 0.f}, 0, 0, 0);
      sc[sn] = __builtin_amdgcn_mfma_f32_16x16x32_bf16(kf[sn][1], aq[1], t, 0, 0, 0);
    }
    __builtin_amdgcn_s_setprio(0);

    // prefetch next tile's K (wraps on last iter; harmless)
    const int sbn = (sbi < 15) ? (sb + 64) : 0;
    #pragma unroll
    for (int sn = 0; sn < 4; sn++)
      #pragma unroll
      for (int k2 = 0; k2 < 2; k2++) {
        const unsigned short* p = Kb + ((sbn >> 2) + sn * 4 + k2 * 2) * 256;
        kf[sn][k2] = cat8(*reinterpret_cast<const s16x4*>(p),
                          *reinterpret_cast<const s16x4*>(p + 64));
      }

    // V frags (A-operand now: row=c, k=s; same addresses)
    bf16x8 bv[4][2];
    #pragma unroll
    for (int cn = 0; cn < 4; cn++)
      #pragma unroll
      for (int k2 = 0; k2 < 2; k2++) {
        const unsigned short* p = Vb + (cn * 64 + (sb >> 4) + k2 * 2) * 256;
        bv[cn][k2] = cat8(*reinterpret_cast<const s16x4*>(p),
                          *reinterpret_cast<const s16x4*>(p + 64));
      }

    // ---- lane-local softmax (query t = t0 + w*16 + lr) ----
    float mx = fmaxf(fmaxf(hmax4(sc[0]), hmax4(sc[1])),
                     fmaxf(hmax4(sc[2]), hmax4(sc[3]))) * SC2;
    mx = fmaxf(mx, __shfl_xor(mx, 16));
    mx = fmaxf(mx, __shfl_xor(mx, 32));
    if (!__all(mx <= mrow + 8.f)) {              // defer-max (T13, log2 units)
      const float mn = fmaxf(mrow, mx);
      const float rsc = exp2f(mrow - mn);
      mrow = mn;
      lrow *= rsc;
      #pragma unroll
      for (int cn = 0; cn < 4; cn++)
        #pragma unroll
        for (int r = 0; r < 4; r++) opv[cn][r] *= rsc;
    }

    float rs = 0.f;
    #pragma unroll
    for (int sn = 0; sn < 4; sn++) {
      float e0 = exp2f(fmaf(sc[sn][0], SC2, -mrow));
      float e1 = exp2f(fmaf(sc[sn][1], SC2, -mrow));
      float e2 = exp2f(fmaf(sc[sn][2], SC2, -mrow));
      float e3 = exp2f(fmaf(sc[sn][3], SC2, -mrow));
      rs += (e0 + e1) + (e2 + e3);
      ushort4 pk;
      pk.x = f2us(e0); pk.y = f2us(e1); pk.z = f2us(e2); pk.w = f2us(e3);
      // s_blk = sn*4+lg, swizzled by lr&8 -> bank-safe b64 store
      *reinterpret_cast<ushort4*>(&pS[w][lr][((sn * 4 + lg) ^ swz) * 4]) = pk;
    }
    lrow += rs;

    // P B-frag read: k = h*32 + lg*8 + i, swizzle flips h for lr>=8
    const int hx = swz >> 3;
    const bf16x8 bp0 = *reinterpret_cast<const bf16x8*>(&pS[w][lr][(0 ^ hx) * 32 + lg * 8]);
    const bf16x8 bp1 = *reinterpret_cast<const bf16x8*>(&pS[w][lr][(1 ^ hx) * 32 + lg * 8]);

    __builtin_amdgcn_s_setprio(1);
    #pragma unroll
    for (int cn = 0; cn < 4; cn++) {
      opv[cn] = __builtin_amdgcn_mfma_f32_16x16x32_bf16(bv[cn][0], bp0, opv[cn], 0, 0, 0);
      opv[cn] = __builtin_amdgcn_mfma_f32_16x16x32_bf16(bv[cn][1], bp1, opv[cn], 0, 0, 0);
    }
    __builtin_amdgcn_s_setprio(0);
  }

  // final l reduce across lg groups (lanes lr, lr+16, lr+32, lr+48)
  float lt = lrow;
  lt += __shfl_xor(lt, 16);
  lt += __shfl_xor(lt, 32);
  const float linv = 1.f / lt;

  // opv[cn][r] = O[c = cn*16 + lg*4 + r][t = t0 + w*16 + lr]
  // avP packed (row=t, k=c): subtile (rt = t0/16 + w, kt = hh*4+cn),
  // within-offset lg*64 + lr*4 + r -> one ushort4 per cn.
  const int rt = (t0 >> 4) + w;
  unsigned short* dst = avP + (size_t)b * 524288;
  #pragma unroll
  for (int cn = 0; cn < 4; cn++) {
    ushort4 o;
    o.x = f2us(opv[cn][0] * linv);
    o.y = f2us(opv[cn][1] * linv);
    o.z = f2us(opv[cn][2] * linv);
    o.w = f2us(opv[cn][3] * linv);
    *reinterpret_cast<ushort4*>(&dst[((size_t)(rt * 32 + hh * 4 + cn) << 8) + lg * 64 + lr * 4]) = o;
  }
}

extern "C" void kernel_launch(void* const* d_in, const int* in_sizes, int n_in,
                              void* d_out, int out_size, void* d_ws, size_t ws_size,
                              hipStream_t stream) {
  const float* x      = (const float*)d_in[0];
  const float* gn_w   = (const float*)d_in[1];
  const float* gn_b   = (const float*)d_in[2];
  const float* qkv_w  = (const float*)d_in[3];
  const float* qkv_b  = (const float*)d_in[4];
  const float* proj_w = (const float*)d_in[5];
  const float* proj_b = (const float*)d_in[6];
  float* out = (float*)d_out;

  const size_t HT = (size_t)BBB * TTT * CCH;           // 4M elems
  const size_t QK = (size_t)BBB * NHEAD * TTT * CHD;   // 4M elems
  unsigned short* hP  = (unsigned short*)d_ws;         // packed H, 8 MB
  unsigned short* vP  = hP + HT;                       // packed V, 8 MB
  unsigned short* avP = vP + QK;                       // packed avT, 8 MB
  unsigned short* wq  = avP + HT;                      // packed qkv_w, 1.5 MB
  unsigned short* wp  = wq + (size_t)O_QKV * CCH;      // packed proj_w, 0.5 MB
  // Q/K packed live in d_out (16 MB): fully rewritten each launch, consumed
  // by attn before proj overwrites d_out (stream-ordered).
  unsigned short* qPd = (unsigned short*)d_out;
  unsigned short* kPd = qPd + QK;

  const int nslot = (O_QKV + CCH) * CCH / 4;           // 262144
  wpack_kernel<<<dim3(nslot / 256), 256, 0, stream>>>(qkv_w, proj_w, wq, nslot);
  gn_kernel<<<dim3(BBB * NGRP), 256, 0, stream>>>(x, gn_w, gn_b, hP);
  gemm_p<0><<<dim3(TTT / 128, O_QKV / 128, BBB), 256, 0, stream>>>(
      wq, hP, qkv_b, nullptr, qPd, kPd, vP, nullptr, O_QKV);
  attn_p<<<dim3(512), 512, 0, stream>>>(qPd, kPd, vP, avP);
  gemm_p<1><<<dim3(TTT / 128, CCH / 128, BBB), 256, 0, stream>>>(
      wp, avP, proj_b, x, nullptr, nullptr, nullptr, out, CCH);
}